// Round 1
// baseline (721.098 us; speedup 1.0000x reference)
//
#include <hip/hip_runtime.h>

#define B_ 8
#define T_ 4096
#define D_ 1024
#define H_ 8
#define BW_ 128
#define NC_ 16
#define CT_ 256
#define EPS7 1e-7f
#define EPS5 1e-5f

// ---------------------------------------------------------------------------
// K1: block (b, head, chunk). Computes gate_x, gate_a, a, normed_x, and
// per-chunk sum of log(a_clamped). Weights held in registers (64 fp32 per
// gate per thread; thread = (j, half-of-K)).
// ---------------------------------------------------------------------------
__global__ __launch_bounds__(256) void k1_gates(
    const float* __restrict__ x, const float* __restrict__ a_param,
    const float* __restrict__ w_in, const float* __restrict__ b_in,
    const float* __restrict__ w_a, const float* __restrict__ b_a,
    float* __restrict__ Abuf, float* NX, float* __restrict__ CS)
{
  const int bid = blockIdx.x;
  const int k    = bid & (NC_ - 1);
  const int h    = (bid >> 4) & (H_ - 1);
  const int b    = bid >> 7;
  const int tid  = threadIdx.x;
  const int j    = tid & 127;
  const int half = tid >> 7;

  __shared__ float xs[8 * 128];            // 8 t-rows staged
  __shared__ float red[2 * 8 * 128 * 2];   // [half][row][j][gate]

  float wI[64], wA[64];
  {
    const float* wio = w_in + (h * BW_ + half * 64) * BW_ + j;
    const float* wao = w_a  + (h * BW_ + half * 64) * BW_ + j;
    #pragma unroll
    for (int i = 0; i < 64; ++i) { wI[i] = wio[i * BW_]; wA[i] = wao[i * BW_]; }
  }
  const float bI = b_in[h * BW_ + j];
  const float bA = b_a [h * BW_ + j];
  const float ap = a_param[h * BW_ + j];
  // softplus(a_param) + MIN_DECAY (stable form)
  const float cdec = ((ap > 20.f) ? ap : log1pf(__expf(ap))) + 0.001f;

  const int t0 = k * CT_;
  const float* xbase = x + (b * T_ + t0) * D_ + h * BW_;
  float sla = 0.f;

  for (int s = 0; s < CT_ / 8; ++s) {
    __syncthreads();  // protect xs/red from previous stage readers
    {
      const int r  = tid >> 5;
      const int c4 = (tid & 31) << 2;
      *(float4*)(xs + r * 128 + c4) = *(const float4*)(xbase + (s * 8 + r) * D_ + c4);
    }
    __syncthreads();

    float accI[8], accA[8];
    #pragma unroll
    for (int r = 0; r < 8; ++r) {
      float ai = 0.f, aa = 0.f;
      const float4* xv = (const float4*)(xs + r * 128 + half * 64);
      #pragma unroll
      for (int ii = 0; ii < 16; ++ii) {
        float4 v = xv[ii];
        ai = fmaf(v.x, wI[4*ii+0], ai); ai = fmaf(v.y, wI[4*ii+1], ai);
        ai = fmaf(v.z, wI[4*ii+2], ai); ai = fmaf(v.w, wI[4*ii+3], ai);
        aa = fmaf(v.x, wA[4*ii+0], aa); aa = fmaf(v.y, wA[4*ii+1], aa);
        aa = fmaf(v.z, wA[4*ii+2], aa); aa = fmaf(v.w, wA[4*ii+3], aa);
      }
      accI[r] = ai; accA[r] = aa;
    }
    #pragma unroll
    for (int r = 0; r < 8; ++r) {
      red[((half * 8 + r) * 128 + j) * 2 + 0] = accI[r];
      red[((half * 8 + r) * 128 + j) * 2 + 1] = accA[r];
    }
    __syncthreads();

    // epilogue: half 0 -> rows 0..3, half 1 -> rows 4..7
    #pragma unroll
    for (int rr = 0; rr < 4; ++rr) {
      const int r = half * 4 + rr;
      const float yi = red[(r * 128 + j) * 2 + 0] + red[((8 + r) * 128 + j) * 2 + 0] + bI;
      const float ya = red[(r * 128 + j) * 2 + 1] + red[((8 + r) * 128 + j) * 2 + 1] + bA;
      const float gx = __builtin_amdgcn_rcpf(1.f + __expf(-yi));
      const float ga = __builtin_amdgcn_rcpf(1.f + __expf(-ya));
      const float la = -ga * cdec;
      const float a  = fminf(__expf(la), 1.0f - EPS5);
      const float lae = fminf(la, -1.0000186e-05f);     // log(1 - 1e-5)
      const float mult = sqrtf(fmaxf(fmaf(-a, a, 1.0f), EPS5));
      const float nx = xs[r * 128 + j] * gx * mult;
      const int gi = (b * T_ + t0 + s * 8 + r) * D_ + h * BW_ + j;
      Abuf[gi] = a;
      NX[gi]   = nx;
      sla += lae;
    }
  }
  __syncthreads();
  red[half * 128 + j] = sla;
  __syncthreads();
  if (half == 0) {
    CS[(b * NC_ + k) * D_ + h * BW_ + j] = red[j] + red[128 + j];
  }
}

// ---------------------------------------------------------------------------
// K2: exclusive prefix over chunk log-sums -> log q at each chunk start.
// ---------------------------------------------------------------------------
__global__ __launch_bounds__(256) void k2_scan_logs(
    const float* __restrict__ CS, float* __restrict__ LQ)
{
  const int idx = blockIdx.x * 256 + threadIdx.x;   // B_*D_ threads
  const int b = idx >> 10;
  const int d = idx & (D_ - 1);
  float lq = 0.f;
  #pragma unroll
  for (int kk = 0; kk < NC_; ++kk) {
    LQ[(b * NC_ + kk) * D_ + d] = lq;
    lq += CS[(b * NC_ + kk) * D_ + d];
  }
}

// shared per-step scan update. State: c = q_{t-1}, pp = p_{t-1}, aprev = a_{t-1}
__device__ __forceinline__ float scan_r(float c, float pp, float aprev) {
  // r_t = p_t / p_{t-1};  p_t = max(c, 1e-7)
  return (c > EPS7) ? aprev
                    : ((pp > EPS7) ? (EPS7 * __builtin_amdgcn_rcpf(pp)) : 1.0f);
}

// ---------------------------------------------------------------------------
// K3a: per-chunk linear composition summary (A = prod r, B = local scan end).
// ---------------------------------------------------------------------------
__global__ __launch_bounds__(256) void k3_summary(
    const float* __restrict__ Abuf, const float* __restrict__ NX,
    const float* __restrict__ LQ, float* __restrict__ Ak, float* __restrict__ Bk)
{
  const int bid = blockIdx.x;
  const int g = bid & 3;
  const int k = (bid >> 2) & (NC_ - 1);
  const int b = bid >> 6;
  const int d = g * 256 + threadIdx.x;
  const int t0 = k * CT_;
  const int base = (b * T_ + t0) * D_ + d;

  float c, pp, aprev;
  if (k == 0) { c = 1.f; pp = 1.f; aprev = 1.f; }
  else {
    c = __expf(LQ[(b * NC_ + k) * D_ + d]);   // q_{t0-1}
    aprev = Abuf[base - D_];                  // a_{t0-1}
    pp = fmaxf(c / aprev, EPS7);              // p_{t0-1}
  }
  float hv = 0.f, rp = 1.f;
  for (int t = 0; t < CT_; t += 8) {
    float av[8], uv[8];
    #pragma unroll
    for (int i = 0; i < 8; ++i) {
      av[i] = Abuf[base + (t + i) * D_];
      uv[i] = NX[base + (t + i) * D_] + EPS7;
    }
    #pragma unroll
    for (int i = 0; i < 8; ++i) {
      const float p = fmaxf(c, EPS7);
      const float r = scan_r(c, pp, aprev);
      hv = fmaf(r, hv, uv[i]);
      rp *= r;
      c *= av[i]; pp = p; aprev = av[i];
    }
  }
  Ak[(b * NC_ + k) * D_ + d] = rp;
  Bk[(b * NC_ + k) * D_ + d] = hv;
}

// ---------------------------------------------------------------------------
// K3b: chain chunk summaries -> h carry-in per chunk.
// ---------------------------------------------------------------------------
__global__ __launch_bounds__(256) void k3_carry(
    const float* __restrict__ Ak, const float* __restrict__ Bk,
    float* __restrict__ Hc)
{
  const int idx = blockIdx.x * 256 + threadIdx.x;
  const int b = idx >> 10;
  const int d = idx & (D_ - 1);
  float Hv = 0.f;
  #pragma unroll
  for (int kk = 0; kk < NC_; ++kk) {
    const int o = (b * NC_ + kk) * D_ + d;
    Hc[o] = Hv;
    Hv = fmaf(Ak[o], Hv, Bk[o]);
  }
}

// ---------------------------------------------------------------------------
// K3c: seeded full scan, writes h. NXO is read (normed_x) then overwritten
// in place with h (same pointer on purpose -> no __restrict__ on it).
// ---------------------------------------------------------------------------
__global__ __launch_bounds__(256) void k3_scan(
    const float* __restrict__ Abuf, float* NXO,
    const float* __restrict__ LQ, const float* __restrict__ Hc)
{
  const int bid = blockIdx.x;
  const int g = bid & 3;
  const int k = (bid >> 2) & (NC_ - 1);
  const int b = bid >> 6;
  const int d = g * 256 + threadIdx.x;
  const int t0 = k * CT_;
  const int base = (b * T_ + t0) * D_ + d;

  float c, pp, aprev;
  if (k == 0) { c = 1.f; pp = 1.f; aprev = 1.f; }
  else {
    c = __expf(LQ[(b * NC_ + k) * D_ + d]);
    aprev = Abuf[base - D_];
    pp = fmaxf(c / aprev, EPS7);
  }
  float hv = Hc[(b * NC_ + k) * D_ + d];
  for (int t = 0; t < CT_; t += 8) {
    float av[8], uv[8];
    #pragma unroll
    for (int i = 0; i < 8; ++i) {
      av[i] = Abuf[base + (t + i) * D_];
      uv[i] = NXO[base + (t + i) * D_] + EPS7;
    }
    #pragma unroll
    for (int i = 0; i < 8; ++i) {
      const float p = fmaxf(c, EPS7);
      const float r = scan_r(c, pp, aprev);
      hv = fmaf(r, hv, uv[i]);
      NXO[base + (t + i) * D_] = hv;
      c *= av[i]; pp = p; aprev = av[i];
    }
  }
}

extern "C" void kernel_launch(void* const* d_in, const int* in_sizes, int n_in,
                              void* d_out, int out_size, void* d_ws, size_t ws_size,
                              hipStream_t stream) {
  const float* x       = (const float*)d_in[0];
  const float* a_param = (const float*)d_in[1];
  const float* w_in    = (const float*)d_in[2];
  const float* b_in    = (const float*)d_in[3];
  const float* w_a     = (const float*)d_in[4];
  const float* b_a     = (const float*)d_in[5];
  float* out = (float*)d_out;   // doubles as normed_x scratch

  char* ws = (char*)d_ws;
  float* Abuf = (float*)ws;                             // B*T*D fp32 = 128 MiB
  float* CS   = (float*)(ws + (size_t)B_ * T_ * D_ * 4);
  float* LQ   = CS + B_ * NC_ * D_;
  float* Ak   = LQ + B_ * NC_ * D_;
  float* Bk   = Ak + B_ * NC_ * D_;
  float* Hc   = Bk + B_ * NC_ * D_;

  k1_gates<<<B_ * H_ * NC_, 256, 0, stream>>>(x, a_param, w_in, b_in, w_a, b_a,
                                              Abuf, out, CS);
  k2_scan_logs<<<(B_ * D_) / 256, 256, 0, stream>>>(CS, LQ);
  k3_summary<<<B_ * NC_ * (D_ / 256), 256, 0, stream>>>(Abuf, out, LQ, Ak, Bk);
  k3_carry<<<(B_ * D_) / 256, 256, 0, stream>>>(Ak, Bk, Hc);
  k3_scan<<<B_ * NC_ * (D_ / 256), 256, 0, stream>>>(Abuf, out, LQ, Hc);
}

// Round 2
// 434.522 us; speedup vs baseline: 1.6595x; 1.6595x over previous
//
#include <hip/hip_runtime.h>

#define B_ 8
#define T_ 4096
#define D_ 1024
#define H_ 8
#define BW_ 128
#define NC_ 32
#define CT_ 128
#define EPS7 1e-7f
#define EPS5 1e-5f
#define LOG1MEPS -1.0000186e-05f   // log(1 - 1e-5)

typedef _Float16 f16x8 __attribute__((ext_vector_type(8)));
typedef _Float16 f16x4 __attribute__((ext_vector_type(4)));
typedef float f32x4 __attribute__((ext_vector_type(4)));

// ---------------------------------------------------------------------------
// K1: block (b, head, 128-row chunk). Gate matmuls on MFMA f16 (16x16x32).
// 4 waves; wave owns 32 j-columns x all 128 rows. Weights live in B-frag
// registers (loaded once, L2-hot); x staged to LDS as f16 (padded stride 136).
// Epilogue: sigmoid/exp nonlinearity in fp32 (x re-read from global, L2-hot),
// writes a -> Abuf, normed_x -> NX, per-chunk sum log(a) -> CS.
// ---------------------------------------------------------------------------
__global__ __launch_bounds__(256) void k1_gates(
    const float* __restrict__ x, const float* __restrict__ a_param,
    const float* __restrict__ w_in, const float* __restrict__ b_in,
    const float* __restrict__ w_a, const float* __restrict__ b_a,
    float* __restrict__ Abuf, float* __restrict__ NX, float* __restrict__ CS)
{
  const int bid  = blockIdx.x;
  const int kc   = bid & (NC_ - 1);
  const int h    = (bid >> 5) & (H_ - 1);
  const int b    = bid >> 8;
  const int tid  = threadIdx.x;
  const int wave = tid >> 6;
  const int lane = tid & 63;
  const int quad = lane >> 4;
  const int l15  = lane & 15;

  __shared__ _Float16 xs[128 * 136];   // 128 rows x 128 K, pad 8 f16/row

  const float* xg = x + (size_t)(b * T_ + kc * CT_) * D_ + h * BW_;
  const int jc = wave * 32;

  // --- B fragments (weights) straight from global; one-time, L2-hot ---
  // B[k][n] frag: lane holds w[k = kstep*32 + quad*8 + i][n = jc + jt*16 + l15]
  f16x8 bf[2][2][4];   // [gate][jtile][kstep]
  #pragma unroll
  for (int g = 0; g < 2; ++g) {
    const float* wptr = (g ? w_a : w_in) + h * BW_ * BW_;
    #pragma unroll
    for (int jt = 0; jt < 2; ++jt) {
      #pragma unroll
      for (int k = 0; k < 4; ++k) {
        const float* wp = wptr + (k * 32 + quad * 8) * BW_ + jc + jt * 16 + l15;
        f16x8 f;
        #pragma unroll
        for (int i = 0; i < 8; ++i) f[i] = (_Float16)wp[i * BW_];
        bf[g][jt][k] = f;
      }
    }
  }
  // per-lane j constants
  float bI[2], bA[2], cdec[2];
  #pragma unroll
  for (int jt = 0; jt < 2; ++jt) {
    const int j = h * BW_ + jc + jt * 16 + l15;
    bI[jt] = b_in[j];
    bA[jt] = b_a[j];
    const float ap = a_param[j];
    cdec[jt] = ((ap > 20.f) ? ap : log1pf(__expf(ap))) + 0.001f;
  }

  // --- stage x -> LDS f16 ---
  {
    const int row = tid >> 1;
    const int cb  = (tid & 1) * 64;
    #pragma unroll
    for (int i = 0; i < 16; ++i) {
      const float4 v = *(const float4*)(xg + row * D_ + cb + i * 4);
      f16x4 hv = { (_Float16)v.x, (_Float16)v.y, (_Float16)v.z, (_Float16)v.w };
      *(f16x4*)(xs + row * 136 + cb + i * 4) = hv;
    }
  }
  __syncthreads();

  // --- MFMA main loop: 8 m-tiles x 4 k-steps x 2 gates x 2 j-tiles ---
  f32x4 acc[2][2][8];
  #pragma unroll
  for (int g = 0; g < 2; ++g)
    #pragma unroll
    for (int jt = 0; jt < 2; ++jt)
      #pragma unroll
      for (int m = 0; m < 8; ++m)
        acc[g][jt][m] = (f32x4){0.f, 0.f, 0.f, 0.f};

  #pragma unroll
  for (int m = 0; m < 8; ++m) {
    f16x8 af[4];
    #pragma unroll
    for (int k = 0; k < 4; ++k)
      af[k] = *(const f16x8*)(xs + (m * 16 + l15) * 136 + k * 32 + quad * 8);
    #pragma unroll
    for (int k = 0; k < 4; ++k)
      #pragma unroll
      for (int g = 0; g < 2; ++g)
        #pragma unroll
        for (int jt = 0; jt < 2; ++jt)
          acc[g][jt][m] = __builtin_amdgcn_mfma_f32_16x16x32_f16(
              af[k], bf[g][jt][k], acc[g][jt][m], 0, 0, 0);
  }

  // --- epilogue: D layout col = l15, row = m*16 + quad*4 + reg ---
  float sla[2] = {0.f, 0.f};
  const size_t obase = (size_t)(b * T_ + kc * CT_) * D_ + h * BW_;
  #pragma unroll
  for (int m = 0; m < 8; ++m) {
    #pragma unroll
    for (int r = 0; r < 4; ++r) {
      const int row = m * 16 + quad * 4 + r;
      #pragma unroll
      for (int jt = 0; jt < 2; ++jt) {
        const int col = jc + jt * 16 + l15;
        const float yi = acc[0][jt][m][r] + bI[jt];
        const float ya = acc[1][jt][m][r] + bA[jt];
        const float gx = __builtin_amdgcn_rcpf(1.f + __expf(-yi));
        const float ga = __builtin_amdgcn_rcpf(1.f + __expf(-ya));
        const float la = -ga * cdec[jt];
        const float a  = fminf(__expf(la), 1.0f - EPS5);
        const float mult = sqrtf(fmaxf(fmaf(-a, a, 1.0f), EPS5));
        const float xval = xg[row * D_ + col];   // L2-hot re-read (exact fp32)
        const float nx = xval * gx * mult;
        const size_t gi = obase + (size_t)row * D_ + col;
        Abuf[gi] = a;
        NX[gi]   = nx;
        sla[jt] += fminf(la, LOG1MEPS);
      }
    }
  }
  // reduce log-a sums across quads (rows partitioned by quad) and emit CS
  #pragma unroll
  for (int jt = 0; jt < 2; ++jt) {
    sla[jt] += __shfl_xor(sla[jt], 16, 64);
    sla[jt] += __shfl_xor(sla[jt], 32, 64);
  }
  if (quad == 0) {
    const int cs = (b * NC_ + kc) * D_ + h * BW_ + jc;
    CS[cs + l15]      = sla[0];
    CS[cs + 16 + l15] = sla[1];
  }
}

// ---------------------------------------------------------------------------
// K2: in-place exclusive prefix over chunk log-sums (CS -> log q at starts).
// ---------------------------------------------------------------------------
__global__ __launch_bounds__(256) void k2_scan_logs(float* __restrict__ CS)
{
  const int idx = blockIdx.x * 256 + threadIdx.x;   // B_*D_ threads
  const int b = idx >> 10;
  const int d = idx & (D_ - 1);
  float lq = 0.f;
  #pragma unroll
  for (int kk = 0; kk < NC_; ++kk) {
    const int o = (b * NC_ + kk) * D_ + d;
    const float c = CS[o];
    CS[o] = lq;
    lq += c;
  }
}

// shared per-step scan decay. State: c = q_{t-1}, pp = p_{t-1}, aprev = a_{t-1}
__device__ __forceinline__ float scan_r(float c, float pp, float aprev) {
  return (c > EPS7) ? aprev
                    : ((pp > EPS7) ? (EPS7 * __builtin_amdgcn_rcpf(pp)) : 1.0f);
}

// ---------------------------------------------------------------------------
// K3a: per-chunk linear composition summary (A = prod r, B = local scan end).
// ---------------------------------------------------------------------------
__global__ __launch_bounds__(256) void k3_summary(
    const float* __restrict__ Abuf, const float* __restrict__ NX,
    const float* __restrict__ LQ, float* __restrict__ Ak, float* __restrict__ Bk)
{
  const int bid = blockIdx.x;
  const int g = bid & 3;
  const int k = (bid >> 2) & (NC_ - 1);
  const int b = bid >> 7;
  const int d = g * 256 + threadIdx.x;
  const int t0 = k * CT_;
  const size_t base = (size_t)(b * T_ + t0) * D_ + d;

  float c, pp, aprev;
  if (k == 0) { c = 1.f; pp = 1.f; aprev = 1.f; }
  else {
    c = __expf(LQ[(b * NC_ + k) * D_ + d]);   // q_{t0-1}
    aprev = Abuf[base - D_];                  // a_{t0-1}
    pp = fmaxf(c / aprev, EPS7);              // p_{t0-1}
  }
  float hv = 0.f, rp = 1.f;
  for (int t = 0; t < CT_; t += 8) {
    float av[8], uv[8];
    #pragma unroll
    for (int i = 0; i < 8; ++i) {
      av[i] = Abuf[base + (size_t)(t + i) * D_];
      uv[i] = NX[base + (size_t)(t + i) * D_] + EPS7;
    }
    #pragma unroll
    for (int i = 0; i < 8; ++i) {
      const float p = fmaxf(c, EPS7);
      const float r = scan_r(c, pp, aprev);
      hv = fmaf(r, hv, uv[i]);
      rp *= r;
      c *= av[i]; pp = p; aprev = av[i];
    }
  }
  Ak[(b * NC_ + k) * D_ + d] = rp;
  Bk[(b * NC_ + k) * D_ + d] = hv;
}

// ---------------------------------------------------------------------------
// K3b: chain chunk summaries -> h carry-in per chunk (in place: Ak -> Hc).
// ---------------------------------------------------------------------------
__global__ __launch_bounds__(256) void k3_carry(
    float* __restrict__ Ak, const float* __restrict__ Bk)
{
  const int idx = blockIdx.x * 256 + threadIdx.x;
  const int b = idx >> 10;
  const int d = idx & (D_ - 1);
  float Hv = 0.f;
  #pragma unroll
  for (int kk = 0; kk < NC_; ++kk) {
    const int o = (b * NC_ + kk) * D_ + d;
    const float Av = Ak[o];
    Ak[o] = Hv;
    Hv = fmaf(Av, Hv, Bk[o]);
  }
}

// ---------------------------------------------------------------------------
// K3c: seeded full scan, writes h. NXO read (normed_x) then overwritten with h.
// ---------------------------------------------------------------------------
__global__ __launch_bounds__(256) void k3_scan(
    const float* __restrict__ Abuf, float* NXO,
    const float* __restrict__ LQ, const float* __restrict__ Hc)
{
  const int bid = blockIdx.x;
  const int g = bid & 3;
  const int k = (bid >> 2) & (NC_ - 1);
  const int b = bid >> 7;
  const int d = g * 256 + threadIdx.x;
  const int t0 = k * CT_;
  const size_t base = (size_t)(b * T_ + t0) * D_ + d;

  float c, pp, aprev;
  if (k == 0) { c = 1.f; pp = 1.f; aprev = 1.f; }
  else {
    c = __expf(LQ[(b * NC_ + k) * D_ + d]);
    aprev = Abuf[base - D_];
    pp = fmaxf(c / aprev, EPS7);
  }
  float hv = Hc[(b * NC_ + k) * D_ + d];
  for (int t = 0; t < CT_; t += 8) {
    float av[8], uv[8];
    #pragma unroll
    for (int i = 0; i < 8; ++i) {
      av[i] = Abuf[base + (size_t)(t + i) * D_];
      uv[i] = NXO[base + (size_t)(t + i) * D_] + EPS7;
    }
    #pragma unroll
    for (int i = 0; i < 8; ++i) {
      const float p = fmaxf(c, EPS7);
      const float r = scan_r(c, pp, aprev);
      hv = fmaf(r, hv, uv[i]);
      NXO[base + (size_t)(t + i) * D_] = hv;
      c *= av[i]; pp = p; aprev = av[i];
    }
  }
}

extern "C" void kernel_launch(void* const* d_in, const int* in_sizes, int n_in,
                              void* d_out, int out_size, void* d_ws, size_t ws_size,
                              hipStream_t stream) {
  const float* x       = (const float*)d_in[0];
  const float* a_param = (const float*)d_in[1];
  const float* w_in    = (const float*)d_in[2];
  const float* b_in    = (const float*)d_in[3];
  const float* w_a     = (const float*)d_in[4];
  const float* b_a     = (const float*)d_in[5];
  float* out = (float*)d_out;   // doubles as normed_x scratch, then h

  char* ws = (char*)d_ws;
  float* Abuf = (float*)ws;                                  // 128 MiB
  float* CS   = (float*)(ws + (size_t)B_ * T_ * D_ * 4);     // 1 MiB (-> LQ)
  float* Ak   = CS + B_ * NC_ * D_;                          // 1 MiB (-> Hc)
  float* Bk   = Ak + B_ * NC_ * D_;                          // 1 MiB

  k1_gates<<<B_ * H_ * NC_, 256, 0, stream>>>(x, a_param, w_in, b_in, w_a, b_a,
                                              Abuf, out, CS);
  k2_scan_logs<<<(B_ * D_) / 256, 256, 0, stream>>>(CS);
  k3_summary<<<B_ * NC_ * (D_ / 256), 256, 0, stream>>>(Abuf, out, CS, Ak, Bk);
  k3_carry<<<(B_ * D_) / 256, 256, 0, stream>>>(Ak, Bk);
  k3_scan<<<B_ * NC_ * (D_ / 256), 256, 0, stream>>>(Abuf, out, CS, Ak);
}